// Round 15
// baseline (284.265 us; speedup 1.0000x reference)
//
#include <hip/hip_runtime.h>
#include <cstddef>

#define NDIM 256
#define NS   64
#define NPIX 4096

typedef float f32x4 __attribute__((ext_vector_type(4)));
typedef short bf16x8 __attribute__((ext_vector_type(8)));
typedef _Float16 f16x4 __attribute__((ext_vector_type(4)));

__device__ __forceinline__ unsigned short f2bf(float x) {
  union { float f; unsigned int u; } v; v.f = x;
  unsigned int r = (v.u + 0x7fffu + ((v.u >> 16) & 1u)) >> 16;
  return (unsigned short)r;
}
__device__ __forceinline__ float bf2f(unsigned short h) {
  union { unsigned int u; float f; } v; v.u = ((unsigned int)h) << 16;
  return v.f;
}
__device__ __forceinline__ unsigned int h16(uint2 v, int j) {
  unsigned int w = (j & 2) ? v.y : v.x;
  return (j & 1) ? (w >> 16) : (w & 0xffffu);
}

// ---------------- workspace layout (float32 offsets) ----------------
static const size_t OFF_YH  = 0;            // y hi   [64 bbr][64 c][4096 n] u16 (8M f32)
static const size_t OFF_YL  = 8388608;      // y lo
static const size_t OFF_AQH = 16777216;     // exp(q) hi [64 bh][1024 m][256 k] u16
static const size_t OFF_AQL = 25165824;     // exp(q) lo
static const size_t OFF_CST = 33554432;     // folded bias [256]
static const size_t OFF_P   = 33624320;     // P [4 i][64 c2][256 co] fp32
static const size_t OFF_WQH = 33689856;     // wqkv hi [192][64] u16 (6144 f32)
static const size_t OFF_WQL = 33696000;     // wqkv lo
static const size_t OFF_TTH = 33702144;     // T^T hi [64 bh][256 co][256 k] u16 (2M f32)
static const size_t OFF_TTL = 35799296;     // T^T lo (end 37,896,448)
// ctxp [64 tile][64 bbr][1024] OVERLAYS TTH+TTL (ctxp dead before k3b writes Tt)
static const size_t OFF_CTXP = OFF_TTH;
static const size_t OFF_CSP  = 37896448;    // csp [64 tile][64 bbr][64] (262,144 f32)

#define LPITCH 72   // LDS tile pitch (floats): 4 guard + 64 + 4 guard

// ============ K1 v4b: LDS image tile + guard ring (proven r10) ============
template<int K>
__device__ __forceinline__ void k1_body(
    const float* __restrict__ x, const float* __restrict__ w,
    const float* __restrict__ bias, unsigned short* __restrict__ yh,
    unsigned short* __restrict__ yl, int br, float* sx, float* swt) {
  constexpr int HK = K / 2;
  const int tid = threadIdx.x;
  const int ch  = blockIdx.x;
  const int b   = blockIdx.y;
  const int wg = tid & 15, st = tid >> 4;
  const int w0 = wg * 4, h0 = st * 4;
  const size_t base = ((size_t)(b * NDIM + br * NS + ch)) * NPIX;
  const float* xp = x + base;

  {
    const f32x4 z = (f32x4){0.f, 0.f, 0.f, 0.f};
    for (int i = tid; i < (LPITCH * LPITCH / 4); i += 256)
      ((f32x4*)sx)[i] = z;
  }
  if (tid < K * K) swt[tid] = w[ch * K * K + tid];
  const float bc = bias[ch];
  __syncthreads();

  {
    const int row = tid >> 2, c16 = (tid & 3) << 4;
    const float* gsrc = xp + row * 64 + c16;
    float* ldst = sx + (row + 4) * LPITCH + 4 + c16;
#pragma unroll
    for (int j = 0; j < 4; ++j)
      *(f32x4*)(ldst + j * 4) = *(const f32x4*)(gsrc + j * 4);
  }
  __syncthreads();

  float acc[4][4];
#pragma unroll
  for (int i = 0; i < 4; ++i)
#pragma unroll
    for (int j = 0; j < 4; ++j) acc[i][j] = 0.f;

#pragma unroll
  for (int r = 0; r < 4 + K - 1; ++r) {
    const int iy = h0 - HK + r;
    const float* lrow = sx + (iy + 4) * LPITCH + w0;
    f32x4 a = *(const f32x4*)(lrow);
    f32x4 o = *(const f32x4*)(lrow + 4);
    f32x4 c = *(const f32x4*)(lrow + 8);
    float win[12];
    win[0] = a[0]; win[1] = a[1]; win[2]  = a[2]; win[3]  = a[3];
    win[4] = o[0]; win[5] = o[1]; win[6]  = o[2]; win[7]  = o[3];
    win[8] = c[0]; win[9] = c[1]; win[10] = c[2]; win[11] = c[3];
#pragma unroll
    for (int hh = 0; hh < 4; ++hh) {
      const int dy = r - hh;
      if (dy >= 0 && dy < K) {
#pragma unroll
        for (int dx = 0; dx < K; ++dx) {
          const float wv = swt[dy * K + dx];
#pragma unroll
          for (int wi = 0; wi < 4; ++wi)
            acc[hh][wi] += wv * win[wi + dx + 4 - HK];
        }
      }
    }
  }
#pragma unroll
  for (int hh = 0; hh < 4; ++hh) {
    const int h = h0 + hh;
    f32x4 c = *(const f32x4*)(sx + (h + 4) * LPITCH + 4 + w0);
    float o[4];
    o[0] = fmaxf(acc[hh][0] + bc + c[0], 0.f);
    o[1] = fmaxf(acc[hh][1] + bc + c[1], 0.f);
    o[2] = fmaxf(acc[hh][2] + bc + c[2], 0.f);
    o[3] = fmaxf(acc[hh][3] + bc + c[3], 0.f);
    unsigned short hb[4], lb[4];
#pragma unroll
    for (int j = 0; j < 4; ++j) { hb[j] = f2bf(o[j]); lb[j] = f2bf(o[j] - bf2f(hb[j])); }
    uint2 hv, lv;
    hv.x = (unsigned int)hb[0] | ((unsigned int)hb[1] << 16);
    hv.y = (unsigned int)hb[2] | ((unsigned int)hb[3] << 16);
    lv.x = (unsigned int)lb[0] | ((unsigned int)lb[1] << 16);
    lv.y = (unsigned int)lb[2] | ((unsigned int)lb[3] << 16);
    *(uint2*)(yh + base + h * 64 + w0) = hv;
    *(uint2*)(yl + base + h * 64 + w0) = lv;
  }
}

__global__ __launch_bounds__(256) void k1_all(
    const float* __restrict__ x,
    const float* __restrict__ w3, const float* __restrict__ b3,
    const float* __restrict__ w5, const float* __restrict__ b5,
    const float* __restrict__ w7, const float* __restrict__ b7,
    const float* __restrict__ w9, const float* __restrict__ b9,
    unsigned short* __restrict__ yh, unsigned short* __restrict__ yl) {
  __shared__ __attribute__((aligned(16))) float sx[LPITCH * LPITCH];
  __shared__ __attribute__((aligned(16))) float swt[81];
  switch (blockIdx.z) {
    case 0: k1_body<3>(x, w3, b3, yh, yl, 0, sx, swt); break;
    case 1: k1_body<5>(x, w5, b5, yh, yl, 1, sx, swt); break;
    case 2: k1_body<7>(x, w7, b7, yh, yl, 2, sx, swt); break;
    default: k1_body<9>(x, w9, b9, yh, yl, 3, sx, swt); break;
  }
}

// ============ k_prep: splitw (48 blk) + P precompute (256 blk) + cst (8 blk) ============
__global__ __launch_bounds__(256) void k_prep(
    const float* __restrict__ wq, unsigned short* __restrict__ wh,
    unsigned short* __restrict__ wl,
    const float* __restrict__ wproj, const float* __restrict__ wfin,
    const float* __restrict__ scale, float* __restrict__ P,
    const float* __restrict__ bproj, const float* __restrict__ bfin,
    float* __restrict__ cst) {
  const int bid = blockIdx.x, tid = threadIdx.x;
  if (bid < 48) {
    const int i = bid * 256 + tid;
    float v = wq[i];
    unsigned short hb = f2bf(v);
    wh[i] = hb;
    wl[i] = f2bf(v - bf2f(hb));
  } else if (bid < 304) {
    const int idx = bid - 48;
    const int c2 = idx & 63, i = idx >> 6;
    const int co = tid;
    float s = 0.f;
#pragma unroll 8
    for (int cl = 0; cl < 64; ++cl)
      s += wproj[cl * 64 + c2] * wfin[(size_t)co * 256 + i * 64 + cl];
    P[((size_t)i * 64 + c2) * 256 + co] = scale[i] * s;
  } else {
    const int p = bid - 304;
    const int co = tid;
    float s = (p == 0) ? bfin[co] : 0.f;
#pragma unroll 8
    for (int qq = 0; qq < 32; ++qq) {
      const int ci = p * 32 + qq;
      s += bproj[ci & 63] * scale[ci >> 6] * wfin[(size_t)co * 256 + ci];
    }
    atomicAdd(&cst[co], s);
  }
}

// ============ K2 v8: phase-split GEMM (proven r11) ============
__global__ __launch_bounds__(256, 6) void k2_attn(
    const unsigned short* __restrict__ yh, const unsigned short* __restrict__ yl,
    const unsigned short* __restrict__ wqh, const unsigned short* __restrict__ wql,
    unsigned short* __restrict__ aqh, unsigned short* __restrict__ aql,
    float* __restrict__ csp, float* __restrict__ ctxp) {
  __shared__ __attribute__((aligned(16))) char smem[18432];
  unsigned short* sAh = (unsigned short*)smem;            // [64 n][72 c] pitch 144B
  unsigned short* sAl = (unsigned short*)(smem + 9216);
  float* sEQ = (float*)smem;                              // [64 n][68 cq] overlays stage

  const int tid = threadIdx.x;
  const int n0  = blockIdx.x * 64;
  const int bbr = blockIdx.y;
  const int b = bbr >> 2, br = bbr & 3;
  const int w = tid >> 6, l = tid & 63, lr = l & 15, q = l >> 4;

  // ---- stage y^T tile: 4c x 4n per thread, register transpose, coalesced ----
  {
    const int cq = tid >> 4, nq = tid & 15;
    const int c0 = cq * 4;
    const size_t src = ((size_t)bbr * 64 + c0) * 4096 + n0 + nq * 4;
    uint2 Hc[4], Lc[4];
#pragma unroll
    for (int ic = 0; ic < 4; ++ic) {
      Hc[ic] = *(const uint2*)(yh + src + (size_t)ic * 4096);
      Lc[ic] = *(const uint2*)(yl + src + (size_t)ic * 4096);
    }
#pragma unroll
    for (int j = 0; j < 4; ++j) {
      uint2 hv, lv;
      hv.x = h16(Hc[0], j) | (h16(Hc[1], j) << 16);
      hv.y = h16(Hc[2], j) | (h16(Hc[3], j) << 16);
      lv.x = h16(Lc[0], j) | (h16(Lc[1], j) << 16);
      lv.y = h16(Lc[2], j) | (h16(Lc[3], j) << 16);
      *(uint2*)((char*)sAh + (nq * 4 + j) * 144 + c0 * 2) = hv;
      *(uint2*)((char*)sAl + (nq * 4 + j) * 144 + c0 * 2) = lv;
    }
  }
  __syncthreads();

  // ---- phase 1: K and V GEMMs (shared A-fragment loads) ----
  f32x4 kacc[4], vacc[4];
#pragma unroll
  for (int rt = 0; rt < 4; ++rt) {
    kacc[rt] = (f32x4){0.f, 0.f, 0.f, 0.f};
    vacc[rt] = (f32x4){0.f, 0.f, 0.f, 0.f};
  }
#pragma unroll
  for (int ks = 0; ks < 2; ++ks) {
    const size_t offk = (size_t)(16 * (4 + w) + lr) * 64 + ks * 32 + q * 8;
    const size_t offv = (size_t)(16 * (8 + w) + lr) * 64 + ks * 32 + q * 8;
    bf16x8 Bkh = *(const bf16x8*)(wqh + offk);
    bf16x8 Bkl = *(const bf16x8*)(wql + offk);
    bf16x8 Bvh = *(const bf16x8*)(wqh + offv);
    bf16x8 Bvl = *(const bf16x8*)(wql + offv);
#pragma unroll
    for (int rt = 0; rt < 4; ++rt) {
      bf16x8 Ah = *(const bf16x8*)((char*)sAh + (16 * rt + lr) * 144 + ks * 64 + q * 16);
      bf16x8 Al = *(const bf16x8*)((char*)sAl + (16 * rt + lr) * 144 + ks * 64 + q * 16);
      kacc[rt] = __builtin_amdgcn_mfma_f32_16x16x32_bf16(Ah, Bkh, kacc[rt], 0, 0, 0);
      kacc[rt] = __builtin_amdgcn_mfma_f32_16x16x32_bf16(Ah, Bkl, kacc[rt], 0, 0, 0);
      kacc[rt] = __builtin_amdgcn_mfma_f32_16x16x32_bf16(Al, Bkh, kacc[rt], 0, 0, 0);
      vacc[rt] = __builtin_amdgcn_mfma_f32_16x16x32_bf16(Ah, Bvh, vacc[rt], 0, 0, 0);
      vacc[rt] = __builtin_amdgcn_mfma_f32_16x16x32_bf16(Ah, Bvl, vacc[rt], 0, 0, 0);
      vacc[rt] = __builtin_amdgcn_mfma_f32_16x16x32_bf16(Al, Bvh, vacc[rt], 0, 0, 0);
    }
  }

  // ---- k-softmax + ctx MFMA (consumes kacc/vacc; frees 32 AGPRs) ----
  {
    f32x4 cacc = (f32x4){0.f, 0.f, 0.f, 0.f};
#pragma unroll
    for (int rt = 0; rt < 4; ++rt) {
      f16x4 kh, kl, vh, vl;
#pragma unroll
      for (int ni = 0; ni < 4; ++ni) {
        const float e = __expf(kacc[rt][ni]);
        float s = e;
        s += __shfl_xor(s, 1);
        s += __shfl_xor(s, 2);
        s += __shfl_xor(s, 4);
        s += __shfl_xor(s, 8);
        const float km = e * __builtin_amdgcn_rcpf(s);
        kh[ni] = (_Float16)km;
        kl[ni] = (_Float16)(km - (float)kh[ni]);
        const float vv = vacc[rt][ni];
        vh[ni] = (_Float16)vv;
        vl[ni] = (_Float16)(vv - (float)vh[ni]);
      }
      cacc = __builtin_amdgcn_mfma_f32_16x16x16f16(kh, vh, cacc, 0, 0, 0);
      cacc = __builtin_amdgcn_mfma_f32_16x16x16f16(kl, vh, cacc, 0, 0, 0);
      cacc = __builtin_amdgcn_mfma_f32_16x16x16f16(kh, vl, cacc, 0, 0, 0);
    }
    float* cp = ctxp + ((size_t)blockIdx.x * 64 + bbr) * 1024 + w * 256;
#pragma unroll
    for (int rg = 0; rg < 4; ++rg)
      cp[(q * 4 + rg) * 16 + lr] = cacc[rg];
  }

  // ---- phase 2: Q GEMM (in freed registers) ----
  f32x4 qacc[4];
#pragma unroll
  for (int rt = 0; rt < 4; ++rt) qacc[rt] = (f32x4){0.f, 0.f, 0.f, 0.f};
#pragma unroll
  for (int ks = 0; ks < 2; ++ks) {
    const size_t offq = (size_t)(16 * w + lr) * 64 + ks * 32 + q * 8;
    bf16x8 Bqh = *(const bf16x8*)(wqh + offq);
    bf16x8 Bql = *(const bf16x8*)(wql + offq);
#pragma unroll
    for (int rt = 0; rt < 4; ++rt) {
      bf16x8 Ah = *(const bf16x8*)((char*)sAh + (16 * rt + lr) * 144 + ks * 64 + q * 16);
      bf16x8 Al = *(const bf16x8*)((char*)sAl + (16 * rt + lr) * 144 + ks * 64 + q * 16);
      qacc[rt] = __builtin_amdgcn_mfma_f32_16x16x32_bf16(Ah, Bqh, qacc[rt], 0, 0, 0);
      qacc[rt] = __builtin_amdgcn_mfma_f32_16x16x32_bf16(Ah, Bql, qacc[rt], 0, 0, 0);
      qacc[rt] = __builtin_amdgcn_mfma_f32_16x16x32_bf16(Al, Bqh, qacc[rt], 0, 0, 0);
    }
  }
  __syncthreads();  // sA dead for ALL waves; sEQ overlays

  // ---- exp(q) -> sEQ + in-wave colsum -> csp ----
  float csum = 0.f;
#pragma unroll
  for (int rt = 0; rt < 4; ++rt)
#pragma unroll
    for (int ni = 0; ni < 4; ++ni) {
      const float e = __expf(qacc[rt][ni]);
      sEQ[(16 * rt + 4 * q + ni) * 68 + 16 * w + lr] = e;
      csum += e;
    }
  csum += __shfl_xor(csum, 16);
  csum += __shfl_xor(csum, 32);
  if (q == 0)
    csp[((size_t)blockIdx.x * 64 + bbr) * 64 + w * 16 + lr] = csum;

  // ---- phase B: aq pack + store (reads ONLY own-wave sEQ cols -> no barrier) ----
  {
    const int h = w;
    const int l6 = tid & 63;
    const int ml = l6 >> 2, r = l6 & 3;
    const float* se = sEQ + l6 * 68 + h * 16;
    float E[16];
    *(f32x4*)&E[0]  = *(const f32x4*)(se);
    *(f32x4*)&E[4]  = *(const f32x4*)(se + 4);
    *(f32x4*)&E[8]  = *(const f32x4*)(se + 8);
    *(f32x4*)&E[12] = *(const f32x4*)(se + 12);
    unsigned int oh[8], ol[8];
#pragma unroll
    for (int dp = 0; dp < 8; ++dp) {
      float e0 = E[2 * dp], e1 = E[2 * dp + 1];
      unsigned short h0 = f2bf(e0), h1 = f2bf(e1);
      unsigned short l0 = f2bf(e0 - bf2f(h0)), l1 = f2bf(e1 - bf2f(h1));
      oh[dp] = (unsigned int)h0 | ((unsigned int)h1 << 16);
      ol[dp] = (unsigned int)l0 | ((unsigned int)l1 << 16);
    }
    const size_t base =
        (((size_t)(b * 4 + h)) * 1024 + (n0 >> 2) + ml) * 256 + br * 64 + r * 16;
    *(uint4*)(aqh + base)     = make_uint4(oh[0], oh[1], oh[2], oh[3]);
    *(uint4*)(aqh + base + 8) = make_uint4(oh[4], oh[5], oh[6], oh[7]);
    *(uint4*)(aql + base)     = make_uint4(ol[0], ol[1], ol[2], ol[3]);
    *(uint4*)(aql + base + 8) = make_uint4(ol[4], ol[5], ol[6], ol[7]);
  }
}

// ============ K3r v2: partial reduce 16 tiles -> slot t=16*tq, IN PLACE ============
__global__ __launch_bounds__(256) void k3r(
    float* __restrict__ csp, float* __restrict__ ctxp) {
  const int bbr = blockIdx.x, tq = blockIdx.y, tid = threadIdx.x;
  const int t0 = tq * 16;
  f32x4 a = (f32x4){0.f, 0.f, 0.f, 0.f};
  for (int t = t0; t < t0 + 16; ++t)
    a += *(const f32x4*)&ctxp[((size_t)t * 64 + bbr) * 1024 + tid * 4];
  *(f32x4*)&ctxp[((size_t)t0 * 64 + bbr) * 1024 + tid * 4] = a;
  if (tid < 64) {
    float s = 0.f;
    for (int t = t0; t < t0 + 16; ++t)
      s += csp[((size_t)t * 64 + bbr) * 64 + tid];
    csp[((size_t)t0 * 64 + bbr) * 64 + tid] = s;
  }
}

// ============ K3b: Tt[bh][co][k] (bf16 hi/lo); sums 4 k3r partial slots ============
__global__ __launch_bounds__(256) void k3b_T(
    const float* __restrict__ csp, const float* __restrict__ ctxp,
    const float* __restrict__ P, unsigned short* __restrict__ tth,
    unsigned short* __restrict__ ttl) {
  __shared__ float sctx[1024];
  __shared__ float sinv[64];
  const int tid = threadIdx.x;
  const int co0 = blockIdx.x * 64;
  const int bh  = blockIdx.y;
  const int b = bh >> 2, h = bh & 3;
  {
    const int i = tid >> 6, de4 = (tid & 63) * 4;
    const size_t bbi = (size_t)(b * 4 + i);
    f32x4 s = (f32x4){0.f, 0.f, 0.f, 0.f};
#pragma unroll
    for (int t0 = 0; t0 < 64; t0 += 16)
      s += *(const f32x4*)&ctxp[((size_t)t0 * 64 + bbi) * 1024 + h * 256 + de4];
    *(f32x4*)&sctx[i * 256 + de4] = s;
  }
  if (tid < 64) {
    const int i = tid >> 4, d = tid & 15;
    float s = 0.f;
#pragma unroll
    for (int t0 = 0; t0 < 64; t0 += 16)
      s += csp[((size_t)t0 * 64 + (b * 4 + i)) * 64 + h * 16 + d];
    sinv[tid] = 1.f / s;
  }
  __syncthreads();
  const int co = co0 + (tid & 63);
  const int rq = tid >> 6;
#pragma unroll
  for (int i = 0; i < 4; ++i) {
    float p[16];
#pragma unroll
    for (int e = 0; e < 16; ++e)
      p[e] = P[((size_t)i * 64 + rq * 16 + e) * 256 + co];
    unsigned int oh[8], ol[8];
#pragma unroll
    for (int dp = 0; dp < 8; ++dp) {
      unsigned short hb[2], lb[2];
#pragma unroll
      for (int u = 0; u < 2; ++u) {
        const int d = 2 * dp + u;
        float s = 0.f;
#pragma unroll
        for (int e = 0; e < 16; ++e) s += sctx[i * 256 + d * 16 + e] * p[e];
        s *= sinv[i * 16 + d];
        hb[u] = f2bf(s);
        lb[u] = f2bf(s - bf2f(hb[u]));
      }
      oh[dp] = (unsigned int)hb[0] | ((unsigned int)hb[1] << 16);
      ol[dp] = (unsigned int)lb[0] | ((unsigned int)lb[1] << 16);
    }
    const size_t base = ((size_t)bh * 256 + co) * 256 + i * 64 + rq * 16;
    *(uint4*)(tth + base)     = make_uint4(oh[0], oh[1], oh[2], oh[3]);
    *(uint4*)(tth + base + 8) = make_uint4(oh[4], oh[5], oh[6], oh[7]);
    *(uint4*)(ttl + base)     = make_uint4(ol[0], ol[1], ol[2], ol[3]);
    *(uint4*)(ttl + base + 8) = make_uint4(ol[4], ol[5], ol[6], ol[7]);
  }
}

// ============ K4 v5: v4 + forced 128-reg bucket (256,4) + XCD-chunked swizzle ============
// v4 landed 88 VGPR + 64 AGPR = 152 -> 2 waves/SIMD bucket. (256,4) caps total at
// 128 -> arch must fit 64; the 24-reg gap is addressing (rematerializable) -- the
// smallest forcing step (r7's disaster forced a cap 88 regs below need; this is 24).
// TRIPWIRE: WRITE_SIZE > 70 MB or dur > 60us => spilled => revert to r14 k4.
// XCD swizzle: lin%8 selects XCD; swz=(lin&7)*128+(lin>>3) gives each XCD a
// contiguous 8-bh chunk (2MB Tt, L2-fits) instead of every XCD touching all 64 bh.
// Read via FETCH (expect 104 -> ~60 MB), independent of the register experiment.
__global__ __launch_bounds__(256, 4) void k4_gemm(
    const unsigned short* __restrict__ tth, const unsigned short* __restrict__ ttl,
    const unsigned short* __restrict__ aqh, const unsigned short* __restrict__ aql,
    const float* __restrict__ cst, float* __restrict__ out) {
  __shared__ __attribute__((aligned(16))) char smem[20480];  // 2 bufs x (sBh 5120 + sBl 5120)
  const int tid = threadIdx.x;
  const unsigned lin = blockIdx.y * 16 + blockIdx.x;          // 0..1023
  const unsigned swz = (lin & 7) * 128 + (lin >> 3);          // bijective chunk remap
  const int m0  = (int)(swz & 15) * 64;
  const int bh  = (int)(swz >> 4);
  const int b = bh >> 2, h = bh & 3;
  const int w = tid >> 6, l = tid & 63, lr = l & 15, q = l >> 4;
  const int cobase = w * 64;
  const int part = tid & 3, mr = tid >> 2;

  f32x4 acc[4][4];
#pragma unroll
  for (int ta = 0; ta < 4; ++ta)
#pragma unroll
    for (int tb = 0; tb < 4; ++tb) acc[ta][tb] = (f32x4){0.f, 0.f, 0.f, 0.f};

  const size_t g0 = ((size_t)bh * 1024 + m0 + mr) * 256 + part * 8;
  uint4 pb0 = *(const uint4*)(aqh + g0);
  uint4 pb2 = *(const uint4*)(aql + g0);

  for (int ks = 0; ks < 8; ++ks) {
    char* sB = smem + (ks & 1) * 10240;
    unsigned short* sBh = (unsigned short*)sB;           // [64 m][40 k] pitch 80B
    unsigned short* sBl = (unsigned short*)(sB + 5120);
    *(uint4*)((char*)sBh + mr * 80 + part * 16) = pb0;
    *(uint4*)((char*)sBl + mr * 80 + part * 16) = pb2;
    bf16x8 Ah[4], Al[4];
#pragma unroll
    for (int ta = 0; ta < 4; ++ta) {
      const size_t ai = ((size_t)bh * 256 + cobase + ta * 16 + lr) * 256 + ks * 32 + q * 8;
      Ah[ta] = *(const bf16x8*)(tth + ai);
      Al[ta] = *(const bf16x8*)(ttl + ai);
    }
    __syncthreads();
    if (ks < 7) {
      pb0 = *(const uint4*)(aqh + g0 + (ks + 1) * 32);
      pb2 = *(const uint4*)(aql + g0 + (ks + 1) * 32);
    }
#pragma unroll
    for (int tb = 0; tb < 4; ++tb) {
      const int ml = tb * 16 + lr;
      bf16x8 Bh = *(const bf16x8*)((char*)sBh + ml * 80 + q * 16);
      bf16x8 Bl = *(const bf16x8*)((char*)sBl + ml * 80 + q * 16);
#pragma unroll
      for (int ta = 0; ta < 4; ++ta) {
        acc[ta][tb] = __builtin_amdgcn_mfma_f32_16x16x32_bf16(Ah[ta], Bh, acc[ta][tb], 0, 0, 0);
        acc[ta][tb] = __builtin_amdgcn_mfma_f32_16x16x32_bf16(Ah[ta], Bl, acc[ta][tb], 0, 0, 0);
        acc[ta][tb] = __builtin_amdgcn_mfma_f32_16x16x32_bf16(Al[ta], Bh, acc[ta][tb], 0, 0, 0);
      }
    }
    // no second barrier: next iter writes the OTHER buffer; the buffer just read
    // is rewritten at ks+2, which is ordered after bar(ks+1).
  }

#pragma unroll
  for (int ta = 0; ta < 4; ++ta) {
#pragma unroll
    for (int reg = 0; reg < 4; ++reg) {
      const int co = cobase + ta * 16 + q * 4 + reg;
      const float cc = cst[co];
      const size_t rowb = ((size_t)b * 256 + co) * 4096 + h * 1024;
#pragma unroll
      for (int tb = 0; tb < 4; ++tb) {
        const int m = m0 + tb * 16 + lr;
        out[rowb + m] = acc[ta][tb][reg] + cc;
      }
    }
  }
}

extern "C" void kernel_launch(void* const* d_in, const int* in_sizes, int n_in,
                              void* d_out, int out_size, void* d_ws, size_t ws_size,
                              hipStream_t stream) {
  (void)in_sizes; (void)n_in; (void)out_size; (void)ws_size;
  const float* x     = (const float*)d_in[0];
  const float* dw3   = (const float*)d_in[1];
  const float* db3   = (const float*)d_in[2];
  const float* dw5   = (const float*)d_in[3];
  const float* db5   = (const float*)d_in[4];
  const float* dw7   = (const float*)d_in[5];
  const float* db7   = (const float*)d_in[6];
  const float* dw9   = (const float*)d_in[7];
  const float* db9   = (const float*)d_in[8];
  const float* wqkv  = (const float*)d_in[9];
  const float* wproj = (const float*)d_in[10];
  const float* bproj = (const float*)d_in[11];
  const float* wfin  = (const float*)d_in[12];
  const float* bfin  = (const float*)d_in[13];
  const float* scw   = (const float*)d_in[14];
  float* out = (float*)d_out;
  float* ws  = (float*)d_ws;

  unsigned short* yh  = (unsigned short*)(ws + OFF_YH);
  unsigned short* yl  = (unsigned short*)(ws + OFF_YL);
  unsigned short* aqh = (unsigned short*)(ws + OFF_AQH);
  unsigned short* aql = (unsigned short*)(ws + OFF_AQL);
  float* cst = ws + OFF_CST;
  float* P   = ws + OFF_P;
  unsigned short* wqh = (unsigned short*)(ws + OFF_WQH);
  unsigned short* wql = (unsigned short*)(ws + OFF_WQL);
  unsigned short* tth = (unsigned short*)(ws + OFF_TTH);
  unsigned short* ttl = (unsigned short*)(ws + OFF_TTL);
  float* ctxp = ws + OFF_CTXP;   // overlays tth/ttl (dead before k3b writes them)
  float* csp  = ws + OFF_CSP;

  // zero cst (k_prep's k_const part accumulates atomically)
  hipMemsetAsync(cst, 0, 256 * sizeof(float), stream);

  k_prep<<<312, 256, 0, stream>>>(wqkv, wqh, wql, wproj, wfin, scw, P,
                                  bproj, bfin, cst);

  k1_all<<<dim3(64, 16, 4), 256, 0, stream>>>(x, dw3, db3, dw5, db5, dw7, db7,
                                              dw9, db9, yh, yl);
  k2_attn<<<dim3(64, 64), 256, 0, stream>>>(yh, yl, wqh, wql, aqh, aql, csp, ctxp);
  k3r<<<dim3(64, 4), 256, 0, stream>>>(csp, ctxp);
  k3b_T<<<dim3(4, 64), 256, 0, stream>>>(csp, ctxp, P, tth, ttl);
  k4_gemm<<<dim3(16, 64), 256, 0, stream>>>(tth, ttl, aqh, aql, cst, out);
}

// Round 16
// 271.097 us; speedup vs baseline: 1.0486x; 1.0486x over previous
//
#include <hip/hip_runtime.h>
#include <cstddef>

#define NDIM 256
#define NS   64
#define NPIX 4096

typedef float f32x4 __attribute__((ext_vector_type(4)));
typedef short bf16x8 __attribute__((ext_vector_type(8)));
typedef _Float16 f16x4 __attribute__((ext_vector_type(4)));

__device__ __forceinline__ unsigned short f2bf(float x) {
  union { float f; unsigned int u; } v; v.f = x;
  unsigned int r = (v.u + 0x7fffu + ((v.u >> 16) & 1u)) >> 16;
  return (unsigned short)r;
}
__device__ __forceinline__ float bf2f(unsigned short h) {
  union { unsigned int u; float f; } v; v.u = ((unsigned int)h) << 16;
  return v.f;
}
__device__ __forceinline__ unsigned int h16(uint2 v, int j) {
  unsigned int w = (j & 2) ? v.y : v.x;
  return (j & 1) ? (w >> 16) : (w & 0xffffu);
}

// ---------------- workspace layout (float32 offsets) ----------------
static const size_t OFF_YH  = 0;            // y hi   [64 bbr][64 c][4096 n] u16 (8M f32)
static const size_t OFF_YL  = 8388608;      // y lo
static const size_t OFF_AQH = 16777216;     // exp(q) hi [64 bh][1024 m][256 k] u16
static const size_t OFF_AQL = 25165824;     // exp(q) lo
static const size_t OFF_CST = 33554432;     // folded bias [256]
static const size_t OFF_P   = 33624320;     // P [4 i][64 c2][256 co] fp32
static const size_t OFF_WQH = 33689856;     // wqkv hi [192][64] u16 (6144 f32)
static const size_t OFF_WQL = 33696000;     // wqkv lo
static const size_t OFF_TTH = 33702144;     // T^T hi [64 bh][256 co][256 k] u16 (2M f32)
static const size_t OFF_TTL = 35799296;     // T^T lo (end 37,896,448)
// ctxp [64 tile][64 bbr][1024] OVERLAYS TTH+TTL (ctxp dead before k3b writes Tt)
static const size_t OFF_CTXP = OFF_TTH;
static const size_t OFF_CSP  = 37896448;    // csp [64 tile][64 bbr][64] (262,144 f32)

#define LPITCH 72   // LDS tile pitch (floats): 4 guard + 64 + 4 guard

// ============ K1 v4b: LDS image tile + guard ring (proven r10) ============
template<int K>
__device__ __forceinline__ void k1_body(
    const float* __restrict__ x, const float* __restrict__ w,
    const float* __restrict__ bias, unsigned short* __restrict__ yh,
    unsigned short* __restrict__ yl, int br, float* sx, float* swt) {
  constexpr int HK = K / 2;
  const int tid = threadIdx.x;
  const int ch  = blockIdx.x;
  const int b   = blockIdx.y;
  const int wg = tid & 15, st = tid >> 4;
  const int w0 = wg * 4, h0 = st * 4;
  const size_t base = ((size_t)(b * NDIM + br * NS + ch)) * NPIX;
  const float* xp = x + base;

  {
    const f32x4 z = (f32x4){0.f, 0.f, 0.f, 0.f};
    for (int i = tid; i < (LPITCH * LPITCH / 4); i += 256)
      ((f32x4*)sx)[i] = z;
  }
  if (tid < K * K) swt[tid] = w[ch * K * K + tid];
  const float bc = bias[ch];
  __syncthreads();

  {
    const int row = tid >> 2, c16 = (tid & 3) << 4;
    const float* gsrc = xp + row * 64 + c16;
    float* ldst = sx + (row + 4) * LPITCH + 4 + c16;
#pragma unroll
    for (int j = 0; j < 4; ++j)
      *(f32x4*)(ldst + j * 4) = *(const f32x4*)(gsrc + j * 4);
  }
  __syncthreads();

  float acc[4][4];
#pragma unroll
  for (int i = 0; i < 4; ++i)
#pragma unroll
    for (int j = 0; j < 4; ++j) acc[i][j] = 0.f;

#pragma unroll
  for (int r = 0; r < 4 + K - 1; ++r) {
    const int iy = h0 - HK + r;
    const float* lrow = sx + (iy + 4) * LPITCH + w0;
    f32x4 a = *(const f32x4*)(lrow);
    f32x4 o = *(const f32x4*)(lrow + 4);
    f32x4 c = *(const f32x4*)(lrow + 8);
    float win[12];
    win[0] = a[0]; win[1] = a[1]; win[2]  = a[2]; win[3]  = a[3];
    win[4] = o[0]; win[5] = o[1]; win[6]  = o[2]; win[7]  = o[3];
    win[8] = c[0]; win[9] = c[1]; win[10] = c[2]; win[11] = c[3];
#pragma unroll
    for (int hh = 0; hh < 4; ++hh) {
      const int dy = r - hh;
      if (dy >= 0 && dy < K) {
#pragma unroll
        for (int dx = 0; dx < K; ++dx) {
          const float wv = swt[dy * K + dx];
#pragma unroll
          for (int wi = 0; wi < 4; ++wi)
            acc[hh][wi] += wv * win[wi + dx + 4 - HK];
        }
      }
    }
  }
#pragma unroll
  for (int hh = 0; hh < 4; ++hh) {
    const int h = h0 + hh;
    f32x4 c = *(const f32x4*)(sx + (h + 4) * LPITCH + 4 + w0);
    float o[4];
    o[0] = fmaxf(acc[hh][0] + bc + c[0], 0.f);
    o[1] = fmaxf(acc[hh][1] + bc + c[1], 0.f);
    o[2] = fmaxf(acc[hh][2] + bc + c[2], 0.f);
    o[3] = fmaxf(acc[hh][3] + bc + c[3], 0.f);
    unsigned short hb[4], lb[4];
#pragma unroll
    for (int j = 0; j < 4; ++j) { hb[j] = f2bf(o[j]); lb[j] = f2bf(o[j] - bf2f(hb[j])); }
    uint2 hv, lv;
    hv.x = (unsigned int)hb[0] | ((unsigned int)hb[1] << 16);
    hv.y = (unsigned int)hb[2] | ((unsigned int)hb[3] << 16);
    lv.x = (unsigned int)lb[0] | ((unsigned int)lb[1] << 16);
    lv.y = (unsigned int)lb[2] | ((unsigned int)lb[3] << 16);
    *(uint2*)(yh + base + h * 64 + w0) = hv;
    *(uint2*)(yl + base + h * 64 + w0) = lv;
  }
}

__global__ __launch_bounds__(256) void k1_all(
    const float* __restrict__ x,
    const float* __restrict__ w3, const float* __restrict__ b3,
    const float* __restrict__ w5, const float* __restrict__ b5,
    const float* __restrict__ w7, const float* __restrict__ b7,
    const float* __restrict__ w9, const float* __restrict__ b9,
    unsigned short* __restrict__ yh, unsigned short* __restrict__ yl) {
  __shared__ __attribute__((aligned(16))) float sx[LPITCH * LPITCH];
  __shared__ __attribute__((aligned(16))) float swt[81];
  switch (blockIdx.z) {
    case 0: k1_body<3>(x, w3, b3, yh, yl, 0, sx, swt); break;
    case 1: k1_body<5>(x, w5, b5, yh, yl, 1, sx, swt); break;
    case 2: k1_body<7>(x, w7, b7, yh, yl, 2, sx, swt); break;
    default: k1_body<9>(x, w9, b9, yh, yl, 3, sx, swt); break;
  }
}

// ============ k_prep: splitw (48 blk) + P precompute (256 blk) + cst (8 blk) ============
__global__ __launch_bounds__(256) void k_prep(
    const float* __restrict__ wq, unsigned short* __restrict__ wh,
    unsigned short* __restrict__ wl,
    const float* __restrict__ wproj, const float* __restrict__ wfin,
    const float* __restrict__ scale, float* __restrict__ P,
    const float* __restrict__ bproj, const float* __restrict__ bfin,
    float* __restrict__ cst) {
  const int bid = blockIdx.x, tid = threadIdx.x;
  if (bid < 48) {
    const int i = bid * 256 + tid;
    float v = wq[i];
    unsigned short hb = f2bf(v);
    wh[i] = hb;
    wl[i] = f2bf(v - bf2f(hb));
  } else if (bid < 304) {
    const int idx = bid - 48;
    const int c2 = idx & 63, i = idx >> 6;
    const int co = tid;
    float s = 0.f;
#pragma unroll 8
    for (int cl = 0; cl < 64; ++cl)
      s += wproj[cl * 64 + c2] * wfin[(size_t)co * 256 + i * 64 + cl];
    P[((size_t)i * 64 + c2) * 256 + co] = scale[i] * s;
  } else {
    const int p = bid - 304;
    const int co = tid;
    float s = (p == 0) ? bfin[co] : 0.f;
#pragma unroll 8
    for (int qq = 0; qq < 32; ++qq) {
      const int ci = p * 32 + qq;
      s += bproj[ci & 63] * scale[ci >> 6] * wfin[(size_t)co * 256 + ci];
    }
    atomicAdd(&cst[co], s);
  }
}

// ============ K2 v8: phase-split GEMM (proven r11) ============
__global__ __launch_bounds__(256, 6) void k2_attn(
    const unsigned short* __restrict__ yh, const unsigned short* __restrict__ yl,
    const unsigned short* __restrict__ wqh, const unsigned short* __restrict__ wql,
    unsigned short* __restrict__ aqh, unsigned short* __restrict__ aql,
    float* __restrict__ csp, float* __restrict__ ctxp) {
  __shared__ __attribute__((aligned(16))) char smem[18432];
  unsigned short* sAh = (unsigned short*)smem;            // [64 n][72 c] pitch 144B
  unsigned short* sAl = (unsigned short*)(smem + 9216);
  float* sEQ = (float*)smem;                              // [64 n][68 cq] overlays stage

  const int tid = threadIdx.x;
  const int n0  = blockIdx.x * 64;
  const int bbr = blockIdx.y;
  const int b = bbr >> 2, br = bbr & 3;
  const int w = tid >> 6, l = tid & 63, lr = l & 15, q = l >> 4;

  // ---- stage y^T tile: 4c x 4n per thread, register transpose, coalesced ----
  {
    const int cq = tid >> 4, nq = tid & 15;
    const int c0 = cq * 4;
    const size_t src = ((size_t)bbr * 64 + c0) * 4096 + n0 + nq * 4;
    uint2 Hc[4], Lc[4];
#pragma unroll
    for (int ic = 0; ic < 4; ++ic) {
      Hc[ic] = *(const uint2*)(yh + src + (size_t)ic * 4096);
      Lc[ic] = *(const uint2*)(yl + src + (size_t)ic * 4096);
    }
#pragma unroll
    for (int j = 0; j < 4; ++j) {
      uint2 hv, lv;
      hv.x = h16(Hc[0], j) | (h16(Hc[1], j) << 16);
      hv.y = h16(Hc[2], j) | (h16(Hc[3], j) << 16);
      lv.x = h16(Lc[0], j) | (h16(Lc[1], j) << 16);
      lv.y = h16(Lc[2], j) | (h16(Lc[3], j) << 16);
      *(uint2*)((char*)sAh + (nq * 4 + j) * 144 + c0 * 2) = hv;
      *(uint2*)((char*)sAl + (nq * 4 + j) * 144 + c0 * 2) = lv;
    }
  }
  __syncthreads();

  // ---- phase 1: K and V GEMMs (shared A-fragment loads) ----
  f32x4 kacc[4], vacc[4];
#pragma unroll
  for (int rt = 0; rt < 4; ++rt) {
    kacc[rt] = (f32x4){0.f, 0.f, 0.f, 0.f};
    vacc[rt] = (f32x4){0.f, 0.f, 0.f, 0.f};
  }
#pragma unroll
  for (int ks = 0; ks < 2; ++ks) {
    const size_t offk = (size_t)(16 * (4 + w) + lr) * 64 + ks * 32 + q * 8;
    const size_t offv = (size_t)(16 * (8 + w) + lr) * 64 + ks * 32 + q * 8;
    bf16x8 Bkh = *(const bf16x8*)(wqh + offk);
    bf16x8 Bkl = *(const bf16x8*)(wql + offk);
    bf16x8 Bvh = *(const bf16x8*)(wqh + offv);
    bf16x8 Bvl = *(const bf16x8*)(wql + offv);
#pragma unroll
    for (int rt = 0; rt < 4; ++rt) {
      bf16x8 Ah = *(const bf16x8*)((char*)sAh + (16 * rt + lr) * 144 + ks * 64 + q * 16);
      bf16x8 Al = *(const bf16x8*)((char*)sAl + (16 * rt + lr) * 144 + ks * 64 + q * 16);
      kacc[rt] = __builtin_amdgcn_mfma_f32_16x16x32_bf16(Ah, Bkh, kacc[rt], 0, 0, 0);
      kacc[rt] = __builtin_amdgcn_mfma_f32_16x16x32_bf16(Ah, Bkl, kacc[rt], 0, 0, 0);
      kacc[rt] = __builtin_amdgcn_mfma_f32_16x16x32_bf16(Al, Bkh, kacc[rt], 0, 0, 0);
      vacc[rt] = __builtin_amdgcn_mfma_f32_16x16x32_bf16(Ah, Bvh, vacc[rt], 0, 0, 0);
      vacc[rt] = __builtin_amdgcn_mfma_f32_16x16x32_bf16(Ah, Bvl, vacc[rt], 0, 0, 0);
      vacc[rt] = __builtin_amdgcn_mfma_f32_16x16x32_bf16(Al, Bvh, vacc[rt], 0, 0, 0);
    }
  }

  // ---- k-softmax + ctx MFMA (consumes kacc/vacc; frees 32 AGPRs) ----
  {
    f32x4 cacc = (f32x4){0.f, 0.f, 0.f, 0.f};
#pragma unroll
    for (int rt = 0; rt < 4; ++rt) {
      f16x4 kh, kl, vh, vl;
#pragma unroll
      for (int ni = 0; ni < 4; ++ni) {
        const float e = __expf(kacc[rt][ni]);
        float s = e;
        s += __shfl_xor(s, 1);
        s += __shfl_xor(s, 2);
        s += __shfl_xor(s, 4);
        s += __shfl_xor(s, 8);
        const float km = e * __builtin_amdgcn_rcpf(s);
        kh[ni] = (_Float16)km;
        kl[ni] = (_Float16)(km - (float)kh[ni]);
        const float vv = vacc[rt][ni];
        vh[ni] = (_Float16)vv;
        vl[ni] = (_Float16)(vv - (float)vh[ni]);
      }
      cacc = __builtin_amdgcn_mfma_f32_16x16x16f16(kh, vh, cacc, 0, 0, 0);
      cacc = __builtin_amdgcn_mfma_f32_16x16x16f16(kl, vh, cacc, 0, 0, 0);
      cacc = __builtin_amdgcn_mfma_f32_16x16x16f16(kh, vl, cacc, 0, 0, 0);
    }
    float* cp = ctxp + ((size_t)blockIdx.x * 64 + bbr) * 1024 + w * 256;
#pragma unroll
    for (int rg = 0; rg < 4; ++rg)
      cp[(q * 4 + rg) * 16 + lr] = cacc[rg];
  }

  // ---- phase 2: Q GEMM (in freed registers) ----
  f32x4 qacc[4];
#pragma unroll
  for (int rt = 0; rt < 4; ++rt) qacc[rt] = (f32x4){0.f, 0.f, 0.f, 0.f};
#pragma unroll
  for (int ks = 0; ks < 2; ++ks) {
    const size_t offq = (size_t)(16 * w + lr) * 64 + ks * 32 + q * 8;
    bf16x8 Bqh = *(const bf16x8*)(wqh + offq);
    bf16x8 Bql = *(const bf16x8*)(wql + offq);
#pragma unroll
    for (int rt = 0; rt < 4; ++rt) {
      bf16x8 Ah = *(const bf16x8*)((char*)sAh + (16 * rt + lr) * 144 + ks * 64 + q * 16);
      bf16x8 Al = *(const bf16x8*)((char*)sAl + (16 * rt + lr) * 144 + ks * 64 + q * 16);
      qacc[rt] = __builtin_amdgcn_mfma_f32_16x16x32_bf16(Ah, Bqh, qacc[rt], 0, 0, 0);
      qacc[rt] = __builtin_amdgcn_mfma_f32_16x16x32_bf16(Ah, Bql, qacc[rt], 0, 0, 0);
      qacc[rt] = __builtin_amdgcn_mfma_f32_16x16x32_bf16(Al, Bqh, qacc[rt], 0, 0, 0);
    }
  }
  __syncthreads();  // sA dead for ALL waves; sEQ overlays

  // ---- exp(q) -> sEQ + in-wave colsum -> csp ----
  float csum = 0.f;
#pragma unroll
  for (int rt = 0; rt < 4; ++rt)
#pragma unroll
    for (int ni = 0; ni < 4; ++ni) {
      const float e = __expf(qacc[rt][ni]);
      sEQ[(16 * rt + 4 * q + ni) * 68 + 16 * w + lr] = e;
      csum += e;
    }
  csum += __shfl_xor(csum, 16);
  csum += __shfl_xor(csum, 32);
  if (q == 0)
    csp[((size_t)blockIdx.x * 64 + bbr) * 64 + w * 16 + lr] = csum;

  // ---- phase B: aq pack + store (reads ONLY own-wave sEQ cols -> no barrier) ----
  {
    const int h = w;
    const int l6 = tid & 63;
    const int ml = l6 >> 2, r = l6 & 3;
    const float* se = sEQ + l6 * 68 + h * 16;
    float E[16];
    *(f32x4*)&E[0]  = *(const f32x4*)(se);
    *(f32x4*)&E[4]  = *(const f32x4*)(se + 4);
    *(f32x4*)&E[8]  = *(const f32x4*)(se + 8);
    *(f32x4*)&E[12] = *(const f32x4*)(se + 12);
    unsigned int oh[8], ol[8];
#pragma unroll
    for (int dp = 0; dp < 8; ++dp) {
      float e0 = E[2 * dp], e1 = E[2 * dp + 1];
      unsigned short h0 = f2bf(e0), h1 = f2bf(e1);
      unsigned short l0 = f2bf(e0 - bf2f(h0)), l1 = f2bf(e1 - bf2f(h1));
      oh[dp] = (unsigned int)h0 | ((unsigned int)h1 << 16);
      ol[dp] = (unsigned int)l0 | ((unsigned int)l1 << 16);
    }
    const size_t base =
        (((size_t)(b * 4 + h)) * 1024 + (n0 >> 2) + ml) * 256 + br * 64 + r * 16;
    *(uint4*)(aqh + base)     = make_uint4(oh[0], oh[1], oh[2], oh[3]);
    *(uint4*)(aqh + base + 8) = make_uint4(oh[4], oh[5], oh[6], oh[7]);
    *(uint4*)(aql + base)     = make_uint4(ol[0], ol[1], ol[2], ol[3]);
    *(uint4*)(aql + base + 8) = make_uint4(ol[4], ol[5], ol[6], ol[7]);
  }
}

// ============ K3r v2: partial reduce 16 tiles -> slot t=16*tq, IN PLACE ============
__global__ __launch_bounds__(256) void k3r(
    float* __restrict__ csp, float* __restrict__ ctxp) {
  const int bbr = blockIdx.x, tq = blockIdx.y, tid = threadIdx.x;
  const int t0 = tq * 16;
  f32x4 a = (f32x4){0.f, 0.f, 0.f, 0.f};
  for (int t = t0; t < t0 + 16; ++t)
    a += *(const f32x4*)&ctxp[((size_t)t * 64 + bbr) * 1024 + tid * 4];
  *(f32x4*)&ctxp[((size_t)t0 * 64 + bbr) * 1024 + tid * 4] = a;
  if (tid < 64) {
    float s = 0.f;
    for (int t = t0; t < t0 + 16; ++t)
      s += csp[((size_t)t * 64 + bbr) * 64 + tid];
    csp[((size_t)t0 * 64 + bbr) * 64 + tid] = s;
  }
}

// ============ K3b: Tt[bh][co][k] (bf16 hi/lo); sums 4 k3r partial slots ============
__global__ __launch_bounds__(256) void k3b_T(
    const float* __restrict__ csp, const float* __restrict__ ctxp,
    const float* __restrict__ P, unsigned short* __restrict__ tth,
    unsigned short* __restrict__ ttl) {
  __shared__ float sctx[1024];
  __shared__ float sinv[64];
  const int tid = threadIdx.x;
  const int co0 = blockIdx.x * 64;
  const int bh  = blockIdx.y;
  const int b = bh >> 2, h = bh & 3;
  {
    const int i = tid >> 6, de4 = (tid & 63) * 4;
    const size_t bbi = (size_t)(b * 4 + i);
    f32x4 s = (f32x4){0.f, 0.f, 0.f, 0.f};
#pragma unroll
    for (int t0 = 0; t0 < 64; t0 += 16)
      s += *(const f32x4*)&ctxp[((size_t)t0 * 64 + bbi) * 1024 + h * 256 + de4];
    *(f32x4*)&sctx[i * 256 + de4] = s;
  }
  if (tid < 64) {
    const int i = tid >> 4, d = tid & 15;
    float s = 0.f;
#pragma unroll
    for (int t0 = 0; t0 < 64; t0 += 16)
      s += csp[((size_t)t0 * 64 + (b * 4 + i)) * 64 + h * 16 + d];
    sinv[tid] = 1.f / s;
  }
  __syncthreads();
  const int co = co0 + (tid & 63);
  const int rq = tid >> 6;
#pragma unroll
  for (int i = 0; i < 4; ++i) {
    float p[16];
#pragma unroll
    for (int e = 0; e < 16; ++e)
      p[e] = P[((size_t)i * 64 + rq * 16 + e) * 256 + co];
    unsigned int oh[8], ol[8];
#pragma unroll
    for (int dp = 0; dp < 8; ++dp) {
      unsigned short hb[2], lb[2];
#pragma unroll
      for (int u = 0; u < 2; ++u) {
        const int d = 2 * dp + u;
        float s = 0.f;
#pragma unroll
        for (int e = 0; e < 16; ++e) s += sctx[i * 256 + d * 16 + e] * p[e];
        s *= sinv[i * 16 + d];
        hb[u] = f2bf(s);
        lb[u] = f2bf(s - bf2f(hb[u]));
      }
      oh[dp] = (unsigned int)hb[0] | ((unsigned int)hb[1] << 16);
      ol[dp] = (unsigned int)lb[0] | ((unsigned int)lb[1] << 16);
    }
    const size_t base = ((size_t)bh * 256 + co) * 256 + i * 64 + rq * 16;
    *(uint4*)(tth + base)     = make_uint4(oh[0], oh[1], oh[2], oh[3]);
    *(uint4*)(tth + base + 8) = make_uint4(oh[4], oh[5], oh[6], oh[7]);
    *(uint4*)(ttl + base)     = make_uint4(ol[0], ol[1], ol[2], ol[3]);
    *(uint4*)(ttl + base + 8) = make_uint4(ol[4], ol[5], ol[6], ol[7]);
  }
}

// ============ K4 v6: r14 config (plain bounds, no spill) + XCD-chunked swizzle ============
// r15 decomposition: swizzle = WIN (FETCH 104->68 MB); (256,4) cap = spill
// (WRITE 65.5->105 MB, dur 54->59) -> tripwire fired, cap reverted. v6 = r14's
// k4 (VGPR 88, 2 waves/SIMD, no spill, 54us) + swizzle only.
// swz=(lin&7)*128+(lin>>3): each XCD gets contiguous 8-bh chunk (2MB Tt, L2-fits).
__global__ __launch_bounds__(256) void k4_gemm(
    const unsigned short* __restrict__ tth, const unsigned short* __restrict__ ttl,
    const unsigned short* __restrict__ aqh, const unsigned short* __restrict__ aql,
    const float* __restrict__ cst, float* __restrict__ out) {
  __shared__ __attribute__((aligned(16))) char smem[20480];  // 2 bufs x (sBh 5120 + sBl 5120)
  const int tid = threadIdx.x;
  const unsigned lin = blockIdx.y * 16 + blockIdx.x;          // 0..1023
  const unsigned swz = (lin & 7) * 128 + (lin >> 3);          // bijective chunk remap
  const int m0  = (int)(swz & 15) * 64;
  const int bh  = (int)(swz >> 4);
  const int b = bh >> 2, h = bh & 3;
  const int w = tid >> 6, l = tid & 63, lr = l & 15, q = l >> 4;
  const int cobase = w * 64;
  const int part = tid & 3, mr = tid >> 2;

  f32x4 acc[4][4];
#pragma unroll
  for (int ta = 0; ta < 4; ++ta)
#pragma unroll
    for (int tb = 0; tb < 4; ++tb) acc[ta][tb] = (f32x4){0.f, 0.f, 0.f, 0.f};

  const size_t g0 = ((size_t)bh * 1024 + m0 + mr) * 256 + part * 8;
  uint4 pb0 = *(const uint4*)(aqh + g0);
  uint4 pb2 = *(const uint4*)(aql + g0);

  for (int ks = 0; ks < 8; ++ks) {
    char* sB = smem + (ks & 1) * 10240;
    unsigned short* sBh = (unsigned short*)sB;           // [64 m][40 k] pitch 80B
    unsigned short* sBl = (unsigned short*)(sB + 5120);
    *(uint4*)((char*)sBh + mr * 80 + part * 16) = pb0;
    *(uint4*)((char*)sBl + mr * 80 + part * 16) = pb2;
    bf16x8 Ah[4], Al[4];
#pragma unroll
    for (int ta = 0; ta < 4; ++ta) {
      const size_t ai = ((size_t)bh * 256 + cobase + ta * 16 + lr) * 256 + ks * 32 + q * 8;
      Ah[ta] = *(const bf16x8*)(tth + ai);
      Al[ta] = *(const bf16x8*)(ttl + ai);
    }
    __syncthreads();
    if (ks < 7) {
      pb0 = *(const uint4*)(aqh + g0 + (ks + 1) * 32);
      pb2 = *(const uint4*)(aql + g0 + (ks + 1) * 32);
    }
#pragma unroll
    for (int tb = 0; tb < 4; ++tb) {
      const int ml = tb * 16 + lr;
      bf16x8 Bh = *(const bf16x8*)((char*)sBh + ml * 80 + q * 16);
      bf16x8 Bl = *(const bf16x8*)((char*)sBl + ml * 80 + q * 16);
#pragma unroll
      for (int ta = 0; ta < 4; ++ta) {
        acc[ta][tb] = __builtin_amdgcn_mfma_f32_16x16x32_bf16(Ah[ta], Bh, acc[ta][tb], 0, 0, 0);
        acc[ta][tb] = __builtin_amdgcn_mfma_f32_16x16x32_bf16(Ah[ta], Bl, acc[ta][tb], 0, 0, 0);
        acc[ta][tb] = __builtin_amdgcn_mfma_f32_16x16x32_bf16(Al[ta], Bh, acc[ta][tb], 0, 0, 0);
      }
    }
    // no second barrier: next iter writes the OTHER buffer; the buffer just read
    // is rewritten at ks+2, which is ordered after bar(ks+1).
  }

#pragma unroll
  for (int ta = 0; ta < 4; ++ta) {
#pragma unroll
    for (int reg = 0; reg < 4; ++reg) {
      const int co = cobase + ta * 16 + q * 4 + reg;
      const float cc = cst[co];
      const size_t rowb = ((size_t)b * 256 + co) * 4096 + h * 1024;
#pragma unroll
      for (int tb = 0; tb < 4; ++tb) {
        const int m = m0 + tb * 16 + lr;
        out[rowb + m] = acc[ta][tb][reg] + cc;
      }
    }
  }
}

extern "C" void kernel_launch(void* const* d_in, const int* in_sizes, int n_in,
                              void* d_out, int out_size, void* d_ws, size_t ws_size,
                              hipStream_t stream) {
  (void)in_sizes; (void)n_in; (void)out_size; (void)ws_size;
  const float* x     = (const float*)d_in[0];
  const float* dw3   = (const float*)d_in[1];
  const float* db3   = (const float*)d_in[2];
  const float* dw5   = (const float*)d_in[3];
  const float* db5   = (const float*)d_in[4];
  const float* dw7   = (const float*)d_in[5];
  const float* db7   = (const float*)d_in[6];
  const float* dw9   = (const float*)d_in[7];
  const float* db9   = (const float*)d_in[8];
  const float* wqkv  = (const float*)d_in[9];
  const float* wproj = (const float*)d_in[10];
  const float* bproj = (const float*)d_in[11];
  const float* wfin  = (const float*)d_in[12];
  const float* bfin  = (const float*)d_in[13];
  const float* scw   = (const float*)d_in[14];
  float* out = (float*)d_out;
  float* ws  = (float*)d_ws;

  unsigned short* yh  = (unsigned short*)(ws + OFF_YH);
  unsigned short* yl  = (unsigned short*)(ws + OFF_YL);
  unsigned short* aqh = (unsigned short*)(ws + OFF_AQH);
  unsigned short* aql = (unsigned short*)(ws + OFF_AQL);
  float* cst = ws + OFF_CST;
  float* P   = ws + OFF_P;
  unsigned short* wqh = (unsigned short*)(ws + OFF_WQH);
  unsigned short* wql = (unsigned short*)(ws + OFF_WQL);
  unsigned short* tth = (unsigned short*)(ws + OFF_TTH);
  unsigned short* ttl = (unsigned short*)(ws + OFF_TTL);
  float* ctxp = ws + OFF_CTXP;   // overlays tth/ttl (dead before k3b writes them)
  float* csp  = ws + OFF_CSP;

  // zero cst (k_prep's k_const part accumulates atomically)
  hipMemsetAsync(cst, 0, 256 * sizeof(float), stream);

  k_prep<<<312, 256, 0, stream>>>(wqkv, wqh, wql, wproj, wfin, scw, P,
                                  bproj, bfin, cst);

  k1_all<<<dim3(64, 16, 4), 256, 0, stream>>>(x, dw3, db3, dw5, db5, dw7, db7,
                                              dw9, db9, yh, yl);
  k2_attn<<<dim3(64, 64), 256, 0, stream>>>(yh, yl, wqh, wql, aqh, aql, csp, ctxp);
  k3r<<<dim3(64, 4), 256, 0, stream>>>(csp, ctxp);
  k3b_T<<<dim3(4, 64), 256, 0, stream>>>(csp, ctxp, P, tth, ttl);
  k4_gemm<<<dim3(16, 64), 256, 0, stream>>>(tth, ttl, aqh, aql, cst, out);
}